// Round 17
// baseline (238.454 us; speedup 1.0000x reference)
//
#include <hip/hip_runtime.h>

typedef __attribute__((ext_vector_type(8))) short bf16x8;
typedef __attribute__((ext_vector_type(4))) float f32x4;

// RNE float -> bf16 (finite inputs)
static __device__ __forceinline__ unsigned short f2bf(float f) {
    unsigned int u = __float_as_uint(f);
    unsigned int r = (u + 0x7fffu + ((u >> 16) & 1u)) >> 16;
    return (unsigned short)r;
}
static __device__ __forceinline__ float bf2f(unsigned short h) {
    return __uint_as_float(((unsigned int)h) << 16);
}

// Packed-weight geometry (bf16, fragment-ordered; scales folded in):
//   W0p: [0,2048)      frags nt=0..3             (K=8 zero-padded to 32, *1/sqrt8)
//   W1p: [2048,6144)   frags (nt=0..3, ks=0..1)  (*1/8)
//   W2p: [6144,10240)  frags (nt=0..3, ks=0..1)  (*1/8)
//   W3p: [10240,26624) frags (nt=0..15, ks=0..1) (*1/8)
#define WP_TOTAL 26624

__global__ __launch_bounds__(256) void zero_kernel(int* __restrict__ p, int n)
{
    int i = blockIdx.x * 256 + threadIdx.x;
    if (i < n) p[i] = 0;
}

// ---- prep: weight pack (frag order) + receiver histogram, one dispatch ----
__global__ __launch_bounds__(256) void prep_kernel(
    const float* __restrict__ W0, const float* __restrict__ W1,
    const float* __restrict__ W2, const float* __restrict__ W3,
    unsigned short* __restrict__ Wp,
    const int* __restrict__ recv, int* __restrict__ cnt, int E)
{
    int o = blockIdx.x * 256 + threadIdx.x;
    if (o < WP_TOTAL) {
        float val;
        if (o < 2048) {
            int nt = o >> 9, w = o & 511, lane = w >> 3, j = w & 7;
            int k = (lane >> 4) * 8 + j, n = nt * 16 + (lane & 15);
            val = (k < 8) ? W0[k * 64 + n] * 0.35355339059327373f : 0.f;
        } else if (o < 6144) {
            int oo = o - 2048, fid = oo >> 9, w = oo & 511, lane = w >> 3, j = w & 7;
            int nt = fid >> 1, ks = fid & 1;
            int k = ks * 32 + (lane >> 4) * 8 + j, n = nt * 16 + (lane & 15);
            val = W1[k * 64 + n] * 0.125f;
        } else if (o < 10240) {
            int oo = o - 6144, fid = oo >> 9, w = oo & 511, lane = w >> 3, j = w & 7;
            int nt = fid >> 1, ks = fid & 1;
            int k = ks * 32 + (lane >> 4) * 8 + j, n = nt * 16 + (lane & 15);
            val = W2[k * 64 + n] * 0.125f;
        } else {
            int oo = o - 10240, fid = oo >> 9, w = oo & 511, lane = w >> 3, j = w & 7;
            int nt = fid >> 1, ks = fid & 1;
            int k = ks * 32 + (lane >> 4) * 8 + j, n = nt * 16 + (lane & 15);
            val = W3[k * 256 + n] * 0.125f;
        }
        Wp[o] = f2bf(val);
    }
    if (o < E) atomicAdd(&cnt[recv[o]], 1);
}

// ---- scan: wave-shuffle based, 2 barriers total ----
__global__ __launch_bounds__(1024) void scan_kernel(const int* __restrict__ cnt,
                                                    int* __restrict__ off,
                                                    int* __restrict__ cursor, int N)
{
    __shared__ int wsum[16];
    const int t = threadIdx.x, lane = t & 63, wv = t >> 6;
    const int per = (N + 1023) / 1024;
    const int base = t * per;
    int s = 0;
    for (int i = 0; i < per; ++i) { int idx = base + i; if (idx < N) s += cnt[idx]; }
    int inc = s;
    #pragma unroll
    for (int d = 1; d < 64; d <<= 1) {
        int v = __shfl_up(inc, d, 64);
        if (lane >= d) inc += v;
    }
    if (lane == 63) wsum[wv] = inc;
    __syncthreads();
    if (t == 0) {
        int run = 0;
        #pragma unroll
        for (int w = 0; w < 16; ++w) { int v = wsum[w]; wsum[w] = run; run += v; }
    }
    __syncthreads();
    int run = wsum[wv] + inc - s;        // exclusive prefix for this thread
    for (int i = 0; i < per; ++i) {
        int idx = base + i;
        if (idx < N) { off[idx] = run; cursor[idx] = run; run += cnt[idx]; }
    }
    if (t == 1023) off[N] = wsum[15] + inc;   // grand total = E
}

// ---- fill: CSR edge list + position-ordered streams for the gather ----
__global__ __launch_bounds__(256) void fill_kernel(
    const int*   __restrict__ recv,
    const int*   __restrict__ senders,
    const float* __restrict__ vectors,
    int* __restrict__ cursor,
    int* __restrict__ edge_of,
    int* __restrict__ snd_pos,
    float4* __restrict__ Y4,
    int E)
{
    int i = blockIdx.x * 256 + threadIdx.x;
    if (i < E) {
        int p = atomicAdd(&cursor[recv[i]], 1);
        edge_of[p] = i;
        snd_pos[p] = senders[i];
        float r0 = -vectors[(size_t)i * 3 + 0];
        float r1 = -vectors[(size_t)i * 3 + 1];
        float r2 = -vectors[(size_t)i * 3 + 2];
        float inv = rsqrtf(r0 * r0 + r1 * r1 + r2 * r2);
        const float s3 = 1.7320508075688772f;
        Y4[p] = make_float4(s3 * r0 * inv, s3 * r1 * inv, s3 * r2 * inv, 0.f);
    }
}

// ======================= MFMA radial MLP, CSR-position order =======================
// Wave = 16 positions. W0-W2 staged in 20KB LDS; W3 frags from L2-hot Wp.
// Layer-3 np-outer/g-inner -> lane holds all 4 segments of its channel ->
// direct ushort4 stores into mix4 [E][64][4]. LDS 28672 B -> 5 blocks/CU.
__global__ __launch_bounds__(256) void mlp_pos_kernel(
    const float* __restrict__ radial,
    const int* __restrict__ edge_of,
    const unsigned short* __restrict__ Wp,
    unsigned short* __restrict__ mix4,      // [E][64][4] bf16
    int E)
{
    __shared__ __align__(16) unsigned short sW[10240];
    __shared__ __align__(16) unsigned short sH[4][1024];

    const int t = threadIdx.x;
    {
        int4* dst = (int4*)sW;
        const int4* src = (const int4*)Wp;
        #pragma unroll
        for (int i = 0; i < 5; ++i) dst[t + i * 256] = src[t + i * 256];
    }
    __syncthreads();

    const int wv = t >> 6, l = t & 63;
    const int lrow = l & 15, quad = l >> 4;
    const int p0 = blockIdx.x * 64 + wv * 16;
    if (p0 >= E) return;

    unsigned short* H = sH[wv];

    bf16x8 afr = {0, 0, 0, 0, 0, 0, 0, 0};
    if (quad == 0) {
        int i = p0 + lrow; if (i >= E) i = E - 1;
        int e = edge_of[i];
        const float* rr = radial + (size_t)e * 8;
        float4 ra = *(const float4*)rr;
        float4 rb = *(const float4*)(rr + 4);
        afr[0] = (short)f2bf(ra.x); afr[1] = (short)f2bf(ra.y);
        afr[2] = (short)f2bf(ra.z); afr[3] = (short)f2bf(ra.w);
        afr[4] = (short)f2bf(rb.x); afr[5] = (short)f2bf(rb.y);
        afr[6] = (short)f2bf(rb.z); afr[7] = (short)f2bf(rb.w);
    }
    #pragma unroll
    for (int nt = 0; nt < 4; ++nt) {
        bf16x8 b = *(const bf16x8*)(sW + nt * 512 + l * 8);
        f32x4 z = {0.f, 0.f, 0.f, 0.f};
        f32x4 cf = __builtin_amdgcn_mfma_f32_16x16x32_bf16(afr, b, z, 0, 0, 0);
        #pragma unroll
        for (int r = 0; r < 4; ++r) {
            float v = cf[r];
            float h = v / (1.f + __expf(-v));
            int er = quad * 4 + r;
            int f  = nt * 16 + lrow;
            H[er * 64 + (f ^ ((er & 7) << 3))] = f2bf(h);
        }
    }

    #pragma unroll 1
    for (int L = 0; L < 2; ++L) {
        const unsigned short* WL = sW + 2048 + L * 4096;
        bf16x8 a[2];
        #pragma unroll
        for (int ks = 0; ks < 2; ++ks)
            a[ks] = *(const bf16x8*)(H + lrow * 64 + ((ks * 32 + quad * 8) ^ ((lrow & 7) << 3)));
        f32x4 cf[4];
        #pragma unroll
        for (int nt = 0; nt < 4; ++nt) { f32x4 z = {0.f,0.f,0.f,0.f}; cf[nt] = z; }
        #pragma unroll
        for (int ks = 0; ks < 2; ++ks) {
            #pragma unroll
            for (int nt = 0; nt < 4; ++nt) {
                bf16x8 b = *(const bf16x8*)(WL + (nt * 2 + ks) * 512 + l * 8);
                cf[nt] = __builtin_amdgcn_mfma_f32_16x16x32_bf16(a[ks], b, cf[nt], 0, 0, 0);
            }
        }
        #pragma unroll
        for (int nt = 0; nt < 4; ++nt) {
            #pragma unroll
            for (int r = 0; r < 4; ++r) {
                float v = cf[nt][r];
                float h = v / (1.f + __expf(-v));
                int er = quad * 4 + r;
                int f  = nt * 16 + lrow;
                H[er * 64 + (f ^ ((er & 7) << 3))] = f2bf(h);
            }
        }
    }

    bf16x8 a3[2];
    #pragma unroll
    for (int ks = 0; ks < 2; ++ks)
        a3[ks] = *(const bf16x8*)(H + lrow * 64 + ((ks * 32 + quad * 8) ^ ((lrow & 7) << 3)));

    const unsigned short* W3 = Wp + 10240;
    #pragma unroll 1
    for (int np = 0; np < 4; ++np) {
        f32x4 cf[4];
        #pragma unroll
        for (int g = 0; g < 4; ++g) { f32x4 z = {0.f,0.f,0.f,0.f}; cf[g] = z; }
        #pragma unroll
        for (int ks = 0; ks < 2; ++ks) {
            #pragma unroll
            for (int g = 0; g < 4; ++g) {
                int nt = g * 4 + np;
                bf16x8 b = *(const bf16x8*)(W3 + (nt * 2 + ks) * 512 + l * 8);
                cf[g] = __builtin_amdgcn_mfma_f32_16x16x32_bf16(a3[ks], b, cf[g], 0, 0, 0);
            }
        }
        int c = np * 16 + lrow;
        #pragma unroll
        for (int r = 0; r < 4; ++r) {
            int er = quad * 4 + r;
            if (p0 + er < E) {
                ushort4 u;
                u.x = f2bf(cf[0][r]); u.y = f2bf(cf[1][r]);
                u.z = f2bf(cf[2][r]); u.w = f2bf(cf[3][r]);
                *(ushort4*)&mix4[((size_t)(p0 + er) * 64 + c) * 4] = u;
            }
        }
    }
}

// ======================= gather: 4 nodes per wave, branchless masked ============
// 4 separate accumulator sets + 4 independent snd->nf load chains per loop
// iteration -- the compiler cannot serialize them into one chain. Masked
// (w=0) iterations read a clamped in-bounds position (cache hit) and add 0.
__global__ __launch_bounds__(256, 4) void gather_kernel(
    const float* __restrict__ node_feats,
    const int*   __restrict__ snd_pos,        // [E] position-ordered
    const float4* __restrict__ Y4,            // [E] position-ordered
    const int*   __restrict__ off,
    const unsigned short* __restrict__ mix4,  // [E][64][4] bf16
    float* __restrict__ out, int N)
{
    const int wid  = threadIdx.x >> 6;
    const int lane = threadIdx.x & 63;
    const int nb = (blockIdx.x * 4 + wid) * 4;   // first of this wave's 4 nodes
    if (nb >= N) return;

    const int n0 = nb;
    const int n1 = (nb + 1 < N) ? nb + 1 : N - 1;
    const int n2 = (nb + 2 < N) ? nb + 2 : N - 1;
    const int n3 = (nb + 3 < N) ? nb + 3 : N - 1;

    const int beg0 = off[n0], d0 = off[n0 + 1] - beg0;
    const int beg1 = off[n1], d1 = off[n1 + 1] - beg1;
    const int beg2 = off[n2], d2 = off[n2 + 1] - beg2;
    const int beg3 = off[n3], d3 = off[n3 + 1] - beg3;

    int maxd = d0;
    maxd = (d1 > maxd) ? d1 : maxd;
    maxd = (d2 > maxd) ? d2 : maxd;
    maxd = (d3 > maxd) ? d3 : maxd;

    float A0[8] = {0,0,0,0,0,0,0,0};
    float A1[8] = {0,0,0,0,0,0,0,0};
    float A2[8] = {0,0,0,0,0,0,0,0};
    float A3[8] = {0,0,0,0,0,0,0,0};

    const float is3 = 0.5773502691896258f;

    for (int k = 0; k < maxd; ++k) {
        // clamped positions (always in-bounds; masked iters re-read cached addr)
        int p0 = (d0 > 0) ? beg0 + ((k < d0) ? k : d0 - 1) : 0;
        int p1 = (d1 > 0) ? beg1 + ((k < d1) ? k : d1 - 1) : 0;
        int p2 = (d2 > 0) ? beg2 + ((k < d2) ? k : d2 - 1) : 0;
        int p3 = (d3 > 0) ? beg3 + ((k < d3) ? k : d3 - 1) : 0;
        float w0 = (k < d0) ? 1.f : 0.f;
        float w1 = (k < d1) ? 1.f : 0.f;
        float w2 = (k < d2) ? 1.f : 0.f;
        float w3 = (k < d3) ? 1.f : 0.f;

        // ---- 4 independent load chains ----
        int s0 = snd_pos[p0], s1 = snd_pos[p1], s2 = snd_pos[p2], s3 = snd_pos[p3];
        float4 Ya = Y4[p0], Yb = Y4[p1], Yc = Y4[p2], Yd = Y4[p3];
        ushort4 ma = *(const ushort4*)&mix4[((size_t)p0 * 64 + lane) * 4];
        ushort4 mb = *(const ushort4*)&mix4[((size_t)p1 * 64 + lane) * 4];
        ushort4 mc = *(const ushort4*)&mix4[((size_t)p2 * 64 + lane) * 4];
        ushort4 md = *(const ushort4*)&mix4[((size_t)p3 * 64 + lane) * 4];
        const float* f0p = node_feats + (size_t)s0 * 256;
        const float* f1p = node_feats + (size_t)s1 * 256;
        const float* f2p = node_feats + (size_t)s2 * 256;
        const float* f3p = node_feats + (size_t)s3 * 256;
        float se0 = f0p[lane], se1 = f1p[lane], se2 = f2p[lane], se3 = f3p[lane];
        float v00 = f0p[64+lane*3], v01 = f0p[65+lane*3], v02 = f0p[66+lane*3];
        float v10 = f1p[64+lane*3], v11 = f1p[65+lane*3], v12 = f1p[66+lane*3];
        float v20 = f2p[64+lane*3], v21 = f2p[65+lane*3], v22 = f2p[66+lane*3];
        float v30 = f3p[64+lane*3], v31 = f3p[65+lane*3], v32 = f3p[66+lane*3];

        // ---- math, mask folded into m-values ----
        {
            float m0 = bf2f(ma.x)*w0, m1 = bf2f(ma.y)*w0, m2 = bf2f(ma.z)*w0, m3 = bf2f(ma.w)*w0;
            float tp = (v00*Ya.x + v01*Ya.y + v02*Ya.z) * is3;
            A0[0] += se0*m0;  A0[1] += tp*m1;
            A0[2] += v00*m2;  A0[3] += v01*m2;  A0[4] += v02*m2;
            float sm = se0*m3;
            A0[5] += Ya.x*sm; A0[6] += Ya.y*sm; A0[7] += Ya.z*sm;
        }
        {
            float m0 = bf2f(mb.x)*w1, m1 = bf2f(mb.y)*w1, m2 = bf2f(mb.z)*w1, m3 = bf2f(mb.w)*w1;
            float tp = (v10*Yb.x + v11*Yb.y + v12*Yb.z) * is3;
            A1[0] += se1*m0;  A1[1] += tp*m1;
            A1[2] += v10*m2;  A1[3] += v11*m2;  A1[4] += v12*m2;
            float sm = se1*m3;
            A1[5] += Yb.x*sm; A1[6] += Yb.y*sm; A1[7] += Yb.z*sm;
        }
        {
            float m0 = bf2f(mc.x)*w2, m1 = bf2f(mc.y)*w2, m2 = bf2f(mc.z)*w2, m3 = bf2f(mc.w)*w2;
            float tp = (v20*Yc.x + v21*Yc.y + v22*Yc.z) * is3;
            A2[0] += se2*m0;  A2[1] += tp*m1;
            A2[2] += v20*m2;  A2[3] += v21*m2;  A2[4] += v22*m2;
            float sm = se2*m3;
            A2[5] += Yc.x*sm; A2[6] += Yc.y*sm; A2[7] += Yc.z*sm;
        }
        {
            float m0 = bf2f(md.x)*w3, m1 = bf2f(md.y)*w3, m2 = bf2f(md.z)*w3, m3 = bf2f(md.w)*w3;
            float tp = (v30*Yd.x + v31*Yd.y + v32*Yd.z) * is3;
            A3[0] += se3*m0;  A3[1] += tp*m1;
            A3[2] += v30*m2;  A3[3] += v31*m2;  A3[4] += v32*m2;
            float sm = se3*m3;
            A3[5] += Yd.x*sm; A3[6] += Yd.y*sm; A3[7] += Yd.z*sm;
        }
    }

    const float kk = 0.0625f;
    #pragma unroll
    for (int j = 0; j < 4; ++j) {
        int n = nb + j;
        if (n >= N) break;
        const float* A = (j == 0) ? A0 : (j == 1) ? A1 : (j == 2) ? A2 : A3;
        float* o = out + (size_t)n * 512;
        o[lane]      = A[0] * kk;
        o[64 + lane] = A[1] * kk;
        o[128 + lane * 3 + 0] = A[2] * kk;
        o[128 + lane * 3 + 1] = A[3] * kk;
        o[128 + lane * 3 + 2] = A[4] * kk;
        o[320 + lane * 3 + 0] = A[5] * kk;
        o[320 + lane * 3 + 1] = A[6] * kk;
        o[320 + lane * 3 + 2] = A[7] * kk;
    }
}

// ======================= Fallback path (tiny ws): VALU MLP + atomic scatter ==========
#define HID 64
__global__ __launch_bounds__(256) void mlp_kernel(
    const float* __restrict__ radial,
    const float* __restrict__ W0g, const float* __restrict__ W1g,
    const float* __restrict__ W2g, const float* __restrict__ W3g,
    unsigned short* __restrict__ mix, int e1)
{
    __shared__ float  sHf[HID * 256];
    __shared__ float4 sW4[1024];

    const int t = threadIdx.x;
    const int e = blockIdx.x * 256 + t;
    const bool valid = e < e1;

    if (t < 128) sW4[t] = ((const float4*)W0g)[t];
    __syncthreads();

    float x[8];
    if (valid) {
        float4 ra = ((const float4*)radial)[(size_t)e * 2 + 0];
        float4 rb = ((const float4*)radial)[(size_t)e * 2 + 1];
        x[0]=ra.x; x[1]=ra.y; x[2]=ra.z; x[3]=ra.w;
        x[4]=rb.x; x[5]=rb.y; x[6]=rb.z; x[7]=rb.w;
    } else {
        #pragma unroll
        for (int k = 0; k < 8; ++k) x[k] = 0.f;
    }

    float acc[64];
    #pragma unroll
    for (int j = 0; j < 64; ++j) acc[j] = 0.f;
    #pragma unroll
    for (int k = 0; k < 8; ++k) {
        #pragma unroll
        for (int jq = 0; jq < 16; ++jq) {
            float4 w = sW4[k * 16 + jq];
            acc[jq*4+0] = fmaf(x[k], w.x, acc[jq*4+0]);
            acc[jq*4+1] = fmaf(x[k], w.y, acc[jq*4+1]);
            acc[jq*4+2] = fmaf(x[k], w.z, acc[jq*4+2]);
            acc[jq*4+3] = fmaf(x[k], w.w, acc[jq*4+3]);
        }
    }
    #pragma unroll
    for (int j = 0; j < 64; ++j) {
        float v = acc[j] * 0.35355339059327373f;
        sHf[j * 256 + t] = v / (1.f + __expf(-v));
    }
    __syncthreads();
    #pragma unroll
    for (int i = 0; i < 4; ++i) sW4[t + i * 256] = ((const float4*)W1g)[t + i * 256];
    __syncthreads();

    #pragma unroll
    for (int j = 0; j < 64; ++j) acc[j] = 0.f;
    #pragma unroll 2
    for (int k = 0; k < 64; ++k) {
        float hk = sHf[k * 256 + t];
        #pragma unroll
        for (int jq = 0; jq < 16; ++jq) {
            float4 w = sW4[k * 16 + jq];
            acc[jq*4+0] = fmaf(hk, w.x, acc[jq*4+0]);
            acc[jq*4+1] = fmaf(hk, w.y, acc[jq*4+1]);
            acc[jq*4+2] = fmaf(hk, w.z, acc[jq*4+2]);
            acc[jq*4+3] = fmaf(hk, w.w, acc[jq*4+3]);
        }
    }
    __syncthreads();
    #pragma unroll
    for (int i = 0; i < 4; ++i) sW4[t + i * 256] = ((const float4*)W2g)[t + i * 256];
    #pragma unroll
    for (int j = 0; j < 64; ++j) {
        float v = acc[j] * 0.125f;
        sHf[j * 256 + t] = v / (1.f + __expf(-v));
    }
    __syncthreads();

    #pragma unroll
    for (int j = 0; j < 64; ++j) acc[j] = 0.f;
    #pragma unroll 2
    for (int k = 0; k < 64; ++k) {
        float hk = sHf[k * 256 + t];
        #pragma unroll
        for (int jq = 0; jq < 16; ++jq) {
            float4 w = sW4[k * 16 + jq];
            acc[jq*4+0] = fmaf(hk, w.x, acc[jq*4+0]);
            acc[jq*4+1] = fmaf(hk, w.y, acc[jq*4+1]);
            acc[jq*4+2] = fmaf(hk, w.z, acc[jq*4+2]);
            acc[jq*4+3] = fmaf(hk, w.w, acc[jq*4+3]);
        }
    }
    __syncthreads();
    #pragma unroll
    for (int j = 0; j < 64; ++j) {
        float v = acc[j] * 0.125f;
        sHf[j * 256 + t] = v / (1.f + __expf(-v));
    }

    unsigned short* mrow = mix + (size_t)e * 256;
    #pragma unroll 1
    for (int jt = 0; jt < 4; ++jt) {
        #pragma unroll
        for (int i = 0; i < 4; ++i) {
            int m = t + i * 256;
            sW4[m] = ((const float4*)W3g)[(m >> 4) * 64 + jt * 16 + (m & 15)];
        }
        __syncthreads();

        #pragma unroll
        for (int j = 0; j < 64; ++j) acc[j] = 0.f;
        #pragma unroll 2
        for (int k = 0; k < 64; ++k) {
            float hk = sHf[k * 256 + t];
            #pragma unroll
            for (int jq = 0; jq < 16; ++jq) {
                float4 w = sW4[k * 16 + jq];
                acc[jq*4+0] = fmaf(hk, w.x, acc[jq*4+0]);
                acc[jq*4+1] = fmaf(hk, w.y, acc[jq*4+1]);
                acc[jq*4+2] = fmaf(hk, w.z, acc[jq*4+2]);
                acc[jq*4+3] = fmaf(hk, w.w, acc[jq*4+3]);
            }
        }
        if (valid) {
            #pragma unroll
            for (int j4 = 0; j4 < 16; ++j4) {
                ushort4 u;
                u.x = f2bf(acc[j4*4+0] * 0.125f);
                u.y = f2bf(acc[j4*4+1] * 0.125f);
                u.z = f2bf(acc[j4*4+2] * 0.125f);
                u.w = f2bf(acc[j4*4+3] * 0.125f);
                *reinterpret_cast<ushort4*>(&mrow[jt * 64 + j4 * 4]) = u;
            }
        }
        __syncthreads();
    }
}

__global__ __launch_bounds__(256) void scatter_kernel(
    const float* __restrict__ node_feats,
    const float* __restrict__ vectors,
    const int*   __restrict__ senders,
    const int*   __restrict__ receivers,
    const unsigned short* __restrict__ mix,
    float* __restrict__ out, int e0, int e1)
{
    int wid  = threadIdx.x >> 6;
    int lane = threadIdx.x & 63;
    int e = e0 + blockIdx.x * 4 + wid;
    if (e >= e1) return;

    int snd = senders[e];
    int rcv = receivers[e];

    float r0 = -vectors[(size_t)e * 3 + 0];
    float r1 = -vectors[(size_t)e * 3 + 1];
    float r2 = -vectors[(size_t)e * 3 + 2];
    float inv = rsqrtf(r0 * r0 + r1 * r1 + r2 * r2);
    float Y0 = 1.7320508075688772f * r0 * inv;
    float Y1 = 1.7320508075688772f * r1 * inv;
    float Y2 = 1.7320508075688772f * r2 * inv;

    const float* nf = node_feats + (size_t)snd * 256;
    float s_e = nf[lane];
    float v0 = nf[64 + lane * 3 + 0];
    float v1 = nf[64 + lane * 3 + 1];
    float v2 = nf[64 + lane * 3 + 2];

    float tp_s = (v0 * Y0 + v1 * Y1 + v2 * Y2) * 0.5773502691896258f;

    const unsigned short* m = mix + (size_t)(e - e0) * 256;
    float m0 = bf2f(m[lane]), m1 = bf2f(m[64 + lane]);
    float m2 = bf2f(m[128 + lane]), m3 = bf2f(m[192 + lane]);

    float* orow = out + (size_t)rcv * 512;
    const float kk = 0.0625f;
    atomicAdd(&orow[lane],      s_e  * m0 * kk);
    atomicAdd(&orow[64 + lane], tp_s * m1 * kk);
    float mv = m2 * kk;
    atomicAdd(&orow[128 + lane * 3 + 0], v0 * mv);
    atomicAdd(&orow[128 + lane * 3 + 1], v1 * mv);
    atomicAdd(&orow[128 + lane * 3 + 2], v2 * mv);
    float ms = s_e * m3 * kk;
    atomicAdd(&orow[320 + lane * 3 + 0], Y0 * ms);
    atomicAdd(&orow[320 + lane * 3 + 1], Y1 * ms);
    atomicAdd(&orow[320 + lane * 3 + 2], Y2 * ms);
}

extern "C" void kernel_launch(void* const* d_in, const int* in_sizes, int n_in,
                              void* d_out, int out_size, void* d_ws, size_t ws_size,
                              hipStream_t stream)
{
    const float* node_feats = (const float*)d_in[0];
    const float* vectors    = (const float*)d_in[1];
    const float* radial     = (const float*)d_in[2];
    const int*   senders    = (const int*)d_in[3];
    const int*   receivers  = (const int*)d_in[4];
    const float* W0         = (const float*)d_in[5];
    const float* W1         = (const float*)d_in[6];
    const float* W2         = (const float*)d_in[7];
    const float* W3         = (const float*)d_in[8];
    float* out = (float*)d_out;

    const int E = in_sizes[3];
    const int N = in_sizes[0] / 256;

    size_t mix_bytes = (size_t)E * 64 * 4 * sizeof(unsigned short);   // mix4
    size_t mix_al    = (mix_bytes + 255) & ~(size_t)255;
    size_t int_bytes = (size_t)(N + (N + 1) + N + E + E) * sizeof(int);
    size_t int_al    = (int_bytes + 255) & ~(size_t)255;
    size_t y4_bytes  = (size_t)E * sizeof(float4);
    size_t y4_al     = (y4_bytes + 255) & ~(size_t)255;
    size_t wp_bytes  = (size_t)WP_TOTAL * sizeof(unsigned short);
    size_t need      = mix_al + int_al + y4_al + wp_bytes;

    if (ws_size >= need) {
        // -------- CSR + position-ordered MFMA path --------
        unsigned short* mix4 = (unsigned short*)d_ws;
        int* cnt      = (int*)((char*)d_ws + mix_al);
        int* off      = cnt + N;
        int* cursor   = off + (N + 1);
        int* edge_of  = cursor + N;
        int* snd_pos  = edge_of + E;
        float4* Y4    = (float4*)((char*)d_ws + mix_al + int_al);
        unsigned short* Wp = (unsigned short*)((char*)d_ws + mix_al + int_al + y4_al);

        zero_kernel<<<dim3((N + 255) / 256), dim3(256), 0, stream>>>(cnt, N);

        prep_kernel<<<dim3((E + 255) / 256), dim3(256), 0, stream>>>(
            W0, W1, W2, W3, Wp, receivers, cnt, E);
        scan_kernel<<<dim3(1), dim3(1024), 0, stream>>>(cnt, off, cursor, N);
        fill_kernel<<<dim3((E + 255) / 256), dim3(256), 0, stream>>>(
            receivers, senders, vectors, cursor, edge_of, snd_pos, Y4, E);

        mlp_pos_kernel<<<dim3((E + 63) / 64), dim3(256), 0, stream>>>(
            radial, edge_of, Wp, mix4, E);

        gather_kernel<<<dim3((N + 15) / 16), dim3(256), 0, stream>>>(
            node_feats, snd_pos, Y4, off, mix4, out, N);
    } else {
        // -------- fallback: chunked VALU MLP + atomic scatter --------
        hipMemsetAsync(d_out, 0, (size_t)out_size * sizeof(float), stream);
        size_t per_edge = 256 * sizeof(unsigned short);
        long long chunk_ll = (long long)(ws_size / per_edge);
        int chunk = (chunk_ll > E) ? E : (int)chunk_ll;
        chunk &= ~255;
        if (chunk <= 0) chunk = 256;
        unsigned short* mix = (unsigned short*)d_ws;
        for (int s = 0; s < E; s += chunk) {
            int eend = s + chunk; if (eend > E) eend = E;
            int ne = eend - s;
            mlp_kernel<<<dim3((ne + 255) / 256), dim3(256), 0, stream>>>(
                radial + (size_t)s * 8, W0, W1, W2, W3, mix, ne);
            scatter_kernel<<<dim3((ne + 3) / 4), dim3(256), 0, stream>>>(
                node_feats, vectors, senders, receivers, mix, out, s, eend);
        }
    }
}

// Round 18
// 210.343 us; speedup vs baseline: 1.1336x; 1.1336x over previous
//
#include <hip/hip_runtime.h>

typedef __attribute__((ext_vector_type(8))) short bf16x8;
typedef __attribute__((ext_vector_type(4))) float f32x4;

// RNE float -> bf16 (finite inputs)
static __device__ __forceinline__ unsigned short f2bf(float f) {
    unsigned int u = __float_as_uint(f);
    unsigned int r = (u + 0x7fffu + ((u >> 16) & 1u)) >> 16;
    return (unsigned short)r;
}
static __device__ __forceinline__ float bf2f(unsigned short h) {
    return __uint_as_float(((unsigned int)h) << 16);
}

// Packed-weight geometry (bf16, fragment-ordered; scales folded in):
//   W0p: [0,2048)      frags nt=0..3             (K=8 zero-padded to 32, *1/sqrt8)
//   W1p: [2048,6144)   frags (nt=0..3, ks=0..1)  (*1/8)
//   W2p: [6144,10240)  frags (nt=0..3, ks=0..1)  (*1/8)
//   W3p: [10240,26624) frags (nt=0..15, ks=0..1) (*1/8)
#define WP_TOTAL 26624

__global__ __launch_bounds__(256) void zero_kernel(int* __restrict__ p, int n)
{
    int i = blockIdx.x * 256 + threadIdx.x;
    if (i < n) p[i] = 0;
}

// ---- prep: weight pack (frag order) + receiver histogram, one dispatch ----
__global__ __launch_bounds__(256) void prep_kernel(
    const float* __restrict__ W0, const float* __restrict__ W1,
    const float* __restrict__ W2, const float* __restrict__ W3,
    unsigned short* __restrict__ Wp,
    const int* __restrict__ recv, int* __restrict__ cnt, int E)
{
    int o = blockIdx.x * 256 + threadIdx.x;
    if (o < WP_TOTAL) {
        float val;
        if (o < 2048) {
            int nt = o >> 9, w = o & 511, lane = w >> 3, j = w & 7;
            int k = (lane >> 4) * 8 + j, n = nt * 16 + (lane & 15);
            val = (k < 8) ? W0[k * 64 + n] * 0.35355339059327373f : 0.f;
        } else if (o < 6144) {
            int oo = o - 2048, fid = oo >> 9, w = oo & 511, lane = w >> 3, j = w & 7;
            int nt = fid >> 1, ks = fid & 1;
            int k = ks * 32 + (lane >> 4) * 8 + j, n = nt * 16 + (lane & 15);
            val = W1[k * 64 + n] * 0.125f;
        } else if (o < 10240) {
            int oo = o - 6144, fid = oo >> 9, w = oo & 511, lane = w >> 3, j = w & 7;
            int nt = fid >> 1, ks = fid & 1;
            int k = ks * 32 + (lane >> 4) * 8 + j, n = nt * 16 + (lane & 15);
            val = W2[k * 64 + n] * 0.125f;
        } else {
            int oo = o - 10240, fid = oo >> 9, w = oo & 511, lane = w >> 3, j = w & 7;
            int nt = fid >> 1, ks = fid & 1;
            int k = ks * 32 + (lane >> 4) * 8 + j, n = nt * 16 + (lane & 15);
            val = W3[k * 256 + n] * 0.125f;
        }
        Wp[o] = f2bf(val);
    }
    if (o < E) atomicAdd(&cnt[recv[o]], 1);
}

// ---- scan: wave-shuffle based, 2 barriers total ----
__global__ __launch_bounds__(1024) void scan_kernel(const int* __restrict__ cnt,
                                                    int* __restrict__ off,
                                                    int* __restrict__ cursor, int N)
{
    __shared__ int wsum[16];
    const int t = threadIdx.x, lane = t & 63, wv = t >> 6;
    const int per = (N + 1023) / 1024;
    const int base = t * per;
    int s = 0;
    for (int i = 0; i < per; ++i) { int idx = base + i; if (idx < N) s += cnt[idx]; }
    int inc = s;
    #pragma unroll
    for (int d = 1; d < 64; d <<= 1) {
        int v = __shfl_up(inc, d, 64);
        if (lane >= d) inc += v;
    }
    if (lane == 63) wsum[wv] = inc;
    __syncthreads();
    if (t == 0) {
        int run = 0;
        #pragma unroll
        for (int w = 0; w < 16; ++w) { int v = wsum[w]; wsum[w] = run; run += v; }
    }
    __syncthreads();
    int run = wsum[wv] + inc - s;        // exclusive prefix for this thread
    for (int i = 0; i < per; ++i) {
        int idx = base + i;
        if (idx < N) { off[idx] = run; cursor[idx] = run; run += cnt[idx]; }
    }
    if (t == 1023) off[N] = wsum[15] + inc;   // grand total = E
}

// ---- fill: CSR edge list + position-ordered streams for the gather ----
__global__ __launch_bounds__(256) void fill_kernel(
    const int*   __restrict__ recv,
    const int*   __restrict__ senders,
    const float* __restrict__ vectors,
    int* __restrict__ cursor,
    int* __restrict__ edge_of,
    int* __restrict__ snd_pos,
    float4* __restrict__ Y4,
    int E)
{
    int i = blockIdx.x * 256 + threadIdx.x;
    if (i < E) {
        int p = atomicAdd(&cursor[recv[i]], 1);
        edge_of[p] = i;
        snd_pos[p] = senders[i];
        float r0 = -vectors[(size_t)i * 3 + 0];
        float r1 = -vectors[(size_t)i * 3 + 1];
        float r2 = -vectors[(size_t)i * 3 + 2];
        float inv = rsqrtf(r0 * r0 + r1 * r1 + r2 * r2);
        const float s3 = 1.7320508075688772f;
        Y4[p] = make_float4(s3 * r0 * inv, s3 * r1 * inv, s3 * r2 * inv, 0.f);
    }
}

// ======================= MFMA radial MLP, CSR-position order =======================
// Wave = 16 positions. W0-W2 staged in 20KB LDS; W3 frags from L2-hot Wp.
// Layer-3 np-outer/g-inner -> lane holds all 4 segments of its channel ->
// direct 8B NT stores into mix4 [E][64][4] (streaming, bypass L2 pollution).
// LDS 28672 B -> 5 blocks/CU.
__global__ __launch_bounds__(256) void mlp_pos_kernel(
    const float* __restrict__ radial,
    const int* __restrict__ edge_of,
    const unsigned short* __restrict__ Wp,
    unsigned short* __restrict__ mix4,      // [E][64][4] bf16
    int E)
{
    __shared__ __align__(16) unsigned short sW[10240];
    __shared__ __align__(16) unsigned short sH[4][1024];

    const int t = threadIdx.x;
    {
        int4* dst = (int4*)sW;
        const int4* src = (const int4*)Wp;
        #pragma unroll
        for (int i = 0; i < 5; ++i) dst[t + i * 256] = src[t + i * 256];
    }
    __syncthreads();

    const int wv = t >> 6, l = t & 63;
    const int lrow = l & 15, quad = l >> 4;
    const int p0 = blockIdx.x * 64 + wv * 16;
    if (p0 >= E) return;

    unsigned short* H = sH[wv];

    bf16x8 afr = {0, 0, 0, 0, 0, 0, 0, 0};
    if (quad == 0) {
        int i = p0 + lrow; if (i >= E) i = E - 1;
        int e = edge_of[i];
        const float* rr = radial + (size_t)e * 8;
        float4 ra = *(const float4*)rr;
        float4 rb = *(const float4*)(rr + 4);
        afr[0] = (short)f2bf(ra.x); afr[1] = (short)f2bf(ra.y);
        afr[2] = (short)f2bf(ra.z); afr[3] = (short)f2bf(ra.w);
        afr[4] = (short)f2bf(rb.x); afr[5] = (short)f2bf(rb.y);
        afr[6] = (short)f2bf(rb.z); afr[7] = (short)f2bf(rb.w);
    }
    #pragma unroll
    for (int nt = 0; nt < 4; ++nt) {
        bf16x8 b = *(const bf16x8*)(sW + nt * 512 + l * 8);
        f32x4 z = {0.f, 0.f, 0.f, 0.f};
        f32x4 cf = __builtin_amdgcn_mfma_f32_16x16x32_bf16(afr, b, z, 0, 0, 0);
        #pragma unroll
        for (int r = 0; r < 4; ++r) {
            float v = cf[r];
            float h = v / (1.f + __expf(-v));
            int er = quad * 4 + r;
            int f  = nt * 16 + lrow;
            H[er * 64 + (f ^ ((er & 7) << 3))] = f2bf(h);
        }
    }

    #pragma unroll 1
    for (int L = 0; L < 2; ++L) {
        const unsigned short* WL = sW + 2048 + L * 4096;
        bf16x8 a[2];
        #pragma unroll
        for (int ks = 0; ks < 2; ++ks)
            a[ks] = *(const bf16x8*)(H + lrow * 64 + ((ks * 32 + quad * 8) ^ ((lrow & 7) << 3)));
        f32x4 cf[4];
        #pragma unroll
        for (int nt = 0; nt < 4; ++nt) { f32x4 z = {0.f,0.f,0.f,0.f}; cf[nt] = z; }
        #pragma unroll
        for (int ks = 0; ks < 2; ++ks) {
            #pragma unroll
            for (int nt = 0; nt < 4; ++nt) {
                bf16x8 b = *(const bf16x8*)(WL + (nt * 2 + ks) * 512 + l * 8);
                cf[nt] = __builtin_amdgcn_mfma_f32_16x16x32_bf16(a[ks], b, cf[nt], 0, 0, 0);
            }
        }
        #pragma unroll
        for (int nt = 0; nt < 4; ++nt) {
            #pragma unroll
            for (int r = 0; r < 4; ++r) {
                float v = cf[nt][r];
                float h = v / (1.f + __expf(-v));
                int er = quad * 4 + r;
                int f  = nt * 16 + lrow;
                H[er * 64 + (f ^ ((er & 7) << 3))] = f2bf(h);
            }
        }
    }

    bf16x8 a3[2];
    #pragma unroll
    for (int ks = 0; ks < 2; ++ks)
        a3[ks] = *(const bf16x8*)(H + lrow * 64 + ((ks * 32 + quad * 8) ^ ((lrow & 7) << 3)));

    const unsigned short* W3 = Wp + 10240;
    #pragma unroll 1
    for (int np = 0; np < 4; ++np) {
        f32x4 cf[4];
        #pragma unroll
        for (int g = 0; g < 4; ++g) { f32x4 z = {0.f,0.f,0.f,0.f}; cf[g] = z; }
        #pragma unroll
        for (int ks = 0; ks < 2; ++ks) {
            #pragma unroll
            for (int g = 0; g < 4; ++g) {
                int nt = g * 4 + np;
                bf16x8 b = *(const bf16x8*)(W3 + (nt * 2 + ks) * 512 + l * 8);
                cf[g] = __builtin_amdgcn_mfma_f32_16x16x32_bf16(a3[ks], b, cf[g], 0, 0, 0);
            }
        }
        int c = np * 16 + lrow;
        #pragma unroll
        for (int r = 0; r < 4; ++r) {
            int er = quad * 4 + r;
            if (p0 + er < E) {
                unsigned long long raw =
                    (unsigned long long)f2bf(cf[0][r])
                  | ((unsigned long long)f2bf(cf[1][r]) << 16)
                  | ((unsigned long long)f2bf(cf[2][r]) << 32)
                  | ((unsigned long long)f2bf(cf[3][r]) << 48);
                __builtin_nontemporal_store(raw,
                    (unsigned long long*)&mix4[((size_t)(p0 + er) * 64 + c) * 4]);
            }
        }
    }
}

// ======================= node-parallel gather (R15 structure + NT mix4 loads) ====
__global__ __launch_bounds__(256) void gather_kernel(
    const float* __restrict__ node_feats,
    const int*   __restrict__ snd_pos,        // [E] position-ordered
    const float4* __restrict__ Y4,            // [E] position-ordered
    const int*   __restrict__ off,
    const unsigned short* __restrict__ mix4,  // [E][64][4] bf16
    float* __restrict__ out, int N)
{
    int wid  = threadIdx.x >> 6;
    int lane = threadIdx.x & 63;
    int n = N - 1 - (int)(blockIdx.x * 4 + wid);
    if (n < 0) return;

    int beg = off[n], end = off[n + 1];

    float a0 = 0.f, a1 = 0.f;
    float b0 = 0.f, b1 = 0.f, b2 = 0.f;
    float c0 = 0.f, c1 = 0.f, c2 = 0.f;

    const float is3 = 0.5773502691896258f;

    #pragma unroll 4
    for (int i = beg; i < end; ++i) {
        int snd  = snd_pos[i];                                    // wave-uniform
        float4 Y = Y4[i];                                         // wave-uniform
        const float* nf = node_feats + (size_t)snd * 256;
        float s_e = nf[lane];
        float v0  = nf[64 + lane * 3 + 0];
        float v1  = nf[64 + lane * 3 + 1];
        float v2  = nf[64 + lane * 3 + 2];
        unsigned long long mraw = __builtin_nontemporal_load(
            (const unsigned long long*)&mix4[((size_t)i * 64 + lane) * 4]);

        float m0 = bf2f((unsigned short)(mraw));
        float m1 = bf2f((unsigned short)(mraw >> 16));
        float m2 = bf2f((unsigned short)(mraw >> 32));
        float m3 = bf2f((unsigned short)(mraw >> 48));

        float tp_s = (v0 * Y.x + v1 * Y.y + v2 * Y.z) * is3;

        a0 += s_e * m0;
        a1 += tp_s * m1;
        b0 += v0 * m2; b1 += v1 * m2; b2 += v2 * m2;
        float sm = s_e * m3;
        c0 += Y.x * sm; c1 += Y.y * sm; c2 += Y.z * sm;
    }

    float* o = out + (size_t)n * 512;
    const float kk = 0.0625f;
    o[lane]      = a0 * kk;
    o[64 + lane] = a1 * kk;
    o[128 + lane * 3 + 0] = b0 * kk;
    o[128 + lane * 3 + 1] = b1 * kk;
    o[128 + lane * 3 + 2] = b2 * kk;
    o[320 + lane * 3 + 0] = c0 * kk;
    o[320 + lane * 3 + 1] = c1 * kk;
    o[320 + lane * 3 + 2] = c2 * kk;
}

// ======================= Fallback path (tiny ws): VALU MLP + atomic scatter ==========
#define HID 64
__global__ __launch_bounds__(256) void mlp_kernel(
    const float* __restrict__ radial,
    const float* __restrict__ W0g, const float* __restrict__ W1g,
    const float* __restrict__ W2g, const float* __restrict__ W3g,
    unsigned short* __restrict__ mix, int e1)
{
    __shared__ float  sHf[HID * 256];
    __shared__ float4 sW4[1024];

    const int t = threadIdx.x;
    const int e = blockIdx.x * 256 + t;
    const bool valid = e < e1;

    if (t < 128) sW4[t] = ((const float4*)W0g)[t];
    __syncthreads();

    float x[8];
    if (valid) {
        float4 ra = ((const float4*)radial)[(size_t)e * 2 + 0];
        float4 rb = ((const float4*)radial)[(size_t)e * 2 + 1];
        x[0]=ra.x; x[1]=ra.y; x[2]=ra.z; x[3]=ra.w;
        x[4]=rb.x; x[5]=rb.y; x[6]=rb.z; x[7]=rb.w;
    } else {
        #pragma unroll
        for (int k = 0; k < 8; ++k) x[k] = 0.f;
    }

    float acc[64];
    #pragma unroll
    for (int j = 0; j < 64; ++j) acc[j] = 0.f;
    #pragma unroll
    for (int k = 0; k < 8; ++k) {
        #pragma unroll
        for (int jq = 0; jq < 16; ++jq) {
            float4 w = sW4[k * 16 + jq];
            acc[jq*4+0] = fmaf(x[k], w.x, acc[jq*4+0]);
            acc[jq*4+1] = fmaf(x[k], w.y, acc[jq*4+1]);
            acc[jq*4+2] = fmaf(x[k], w.z, acc[jq*4+2]);
            acc[jq*4+3] = fmaf(x[k], w.w, acc[jq*4+3]);
        }
    }
    #pragma unroll
    for (int j = 0; j < 64; ++j) {
        float v = acc[j] * 0.35355339059327373f;
        sHf[j * 256 + t] = v / (1.f + __expf(-v));
    }
    __syncthreads();
    #pragma unroll
    for (int i = 0; i < 4; ++i) sW4[t + i * 256] = ((const float4*)W1g)[t + i * 256];
    __syncthreads();

    #pragma unroll
    for (int j = 0; j < 64; ++j) acc[j] = 0.f;
    #pragma unroll 2
    for (int k = 0; k < 64; ++k) {
        float hk = sHf[k * 256 + t];
        #pragma unroll
        for (int jq = 0; jq < 16; ++jq) {
            float4 w = sW4[k * 16 + jq];
            acc[jq*4+0] = fmaf(hk, w.x, acc[jq*4+0]);
            acc[jq*4+1] = fmaf(hk, w.y, acc[jq*4+1]);
            acc[jq*4+2] = fmaf(hk, w.z, acc[jq*4+2]);
            acc[jq*4+3] = fmaf(hk, w.w, acc[jq*4+3]);
        }
    }
    __syncthreads();
    #pragma unroll
    for (int i = 0; i < 4; ++i) sW4[t + i * 256] = ((const float4*)W2g)[t + i * 256];
    #pragma unroll
    for (int j = 0; j < 64; ++j) {
        float v = acc[j] * 0.125f;
        sHf[j * 256 + t] = v / (1.f + __expf(-v));
    }
    __syncthreads();

    #pragma unroll
    for (int j = 0; j < 64; ++j) acc[j] = 0.f;
    #pragma unroll 2
    for (int k = 0; k < 64; ++k) {
        float hk = sHf[k * 256 + t];
        #pragma unroll
        for (int jq = 0; jq < 16; ++jq) {
            float4 w = sW4[k * 16 + jq];
            acc[jq*4+0] = fmaf(hk, w.x, acc[jq*4+0]);
            acc[jq*4+1] = fmaf(hk, w.y, acc[jq*4+1]);
            acc[jq*4+2] = fmaf(hk, w.z, acc[jq*4+2]);
            acc[jq*4+3] = fmaf(hk, w.w, acc[jq*4+3]);
        }
    }
    __syncthreads();
    #pragma unroll
    for (int j = 0; j < 64; ++j) {
        float v = acc[j] * 0.125f;
        sHf[j * 256 + t] = v / (1.f + __expf(-v));
    }

    unsigned short* mrow = mix + (size_t)e * 256;
    #pragma unroll 1
    for (int jt = 0; jt < 4; ++jt) {
        #pragma unroll
        for (int i = 0; i < 4; ++i) {
            int m = t + i * 256;
            sW4[m] = ((const float4*)W3g)[(m >> 4) * 64 + jt * 16 + (m & 15)];
        }
        __syncthreads();

        #pragma unroll
        for (int j = 0; j < 64; ++j) acc[j] = 0.f;
        #pragma unroll 2
        for (int k = 0; k < 64; ++k) {
            float hk = sHf[k * 256 + t];
            #pragma unroll
            for (int jq = 0; jq < 16; ++jq) {
                float4 w = sW4[k * 16 + jq];
                acc[jq*4+0] = fmaf(hk, w.x, acc[jq*4+0]);
                acc[jq*4+1] = fmaf(hk, w.y, acc[jq*4+1]);
                acc[jq*4+2] = fmaf(hk, w.z, acc[jq*4+2]);
                acc[jq*4+3] = fmaf(hk, w.w, acc[jq*4+3]);
            }
        }
        if (valid) {
            #pragma unroll
            for (int j4 = 0; j4 < 16; ++j4) {
                ushort4 u;
                u.x = f2bf(acc[j4*4+0] * 0.125f);
                u.y = f2bf(acc[j4*4+1] * 0.125f);
                u.z = f2bf(acc[j4*4+2] * 0.125f);
                u.w = f2bf(acc[j4*4+3] * 0.125f);
                *reinterpret_cast<ushort4*>(&mrow[jt * 64 + j4 * 4]) = u;
            }
        }
        __syncthreads();
    }
}

__global__ __launch_bounds__(256) void scatter_kernel(
    const float* __restrict__ node_feats,
    const float* __restrict__ vectors,
    const int*   __restrict__ senders,
    const int*   __restrict__ receivers,
    const unsigned short* __restrict__ mix,
    float* __restrict__ out, int e0, int e1)
{
    int wid  = threadIdx.x >> 6;
    int lane = threadIdx.x & 63;
    int e = e0 + blockIdx.x * 4 + wid;
    if (e >= e1) return;

    int snd = senders[e];
    int rcv = receivers[e];

    float r0 = -vectors[(size_t)e * 3 + 0];
    float r1 = -vectors[(size_t)e * 3 + 1];
    float r2 = -vectors[(size_t)e * 3 + 2];
    float inv = rsqrtf(r0 * r0 + r1 * r1 + r2 * r2);
    float Y0 = 1.7320508075688772f * r0 * inv;
    float Y1 = 1.7320508075688772f * r1 * inv;
    float Y2 = 1.7320508075688772f * r2 * inv;

    const float* nf = node_feats + (size_t)snd * 256;
    float s_e = nf[lane];
    float v0 = nf[64 + lane * 3 + 0];
    float v1 = nf[64 + lane * 3 + 1];
    float v2 = nf[64 + lane * 3 + 2];

    float tp_s = (v0 * Y0 + v1 * Y1 + v2 * Y2) * 0.5773502691896258f;

    const unsigned short* m = mix + (size_t)(e - e0) * 256;
    float m0 = bf2f(m[lane]), m1 = bf2f(m[64 + lane]);
    float m2 = bf2f(m[128 + lane]), m3 = bf2f(m[192 + lane]);

    float* orow = out + (size_t)rcv * 512;
    const float kk = 0.0625f;
    atomicAdd(&orow[lane],      s_e  * m0 * kk);
    atomicAdd(&orow[64 + lane], tp_s * m1 * kk);
    float mv = m2 * kk;
    atomicAdd(&orow[128 + lane * 3 + 0], v0 * mv);
    atomicAdd(&orow[128 + lane * 3 + 1], v1 * mv);
    atomicAdd(&orow[128 + lane * 3 + 2], v2 * mv);
    float ms = s_e * m3 * kk;
    atomicAdd(&orow[320 + lane * 3 + 0], Y0 * ms);
    atomicAdd(&orow[320 + lane * 3 + 1], Y1 * ms);
    atomicAdd(&orow[320 + lane * 3 + 2], Y2 * ms);
}

extern "C" void kernel_launch(void* const* d_in, const int* in_sizes, int n_in,
                              void* d_out, int out_size, void* d_ws, size_t ws_size,
                              hipStream_t stream)
{
    const float* node_feats = (const float*)d_in[0];
    const float* vectors    = (const float*)d_in[1];
    const float* radial     = (const float*)d_in[2];
    const int*   senders    = (const int*)d_in[3];
    const int*   receivers  = (const int*)d_in[4];
    const float* W0         = (const float*)d_in[5];
    const float* W1         = (const float*)d_in[6];
    const float* W2         = (const float*)d_in[7];
    const float* W3         = (const float*)d_in[8];
    float* out = (float*)d_out;

    const int E = in_sizes[3];
    const int N = in_sizes[0] / 256;

    size_t mix_bytes = (size_t)E * 64 * 4 * sizeof(unsigned short);   // mix4
    size_t mix_al    = (mix_bytes + 255) & ~(size_t)255;
    size_t int_bytes = (size_t)(N + (N + 1) + N + E + E) * sizeof(int);
    size_t int_al    = (int_bytes + 255) & ~(size_t)255;
    size_t y4_bytes  = (size_t)E * sizeof(float4);
    size_t y4_al     = (y4_bytes + 255) & ~(size_t)255;
    size_t wp_bytes  = (size_t)WP_TOTAL * sizeof(unsigned short);
    size_t need      = mix_al + int_al + y4_al + wp_bytes;

    if (ws_size >= need) {
        // -------- CSR + position-ordered MFMA path --------
        unsigned short* mix4 = (unsigned short*)d_ws;
        int* cnt      = (int*)((char*)d_ws + mix_al);
        int* off      = cnt + N;
        int* cursor   = off + (N + 1);
        int* edge_of  = cursor + N;
        int* snd_pos  = edge_of + E;
        float4* Y4    = (float4*)((char*)d_ws + mix_al + int_al);
        unsigned short* Wp = (unsigned short*)((char*)d_ws + mix_al + int_al + y4_al);

        zero_kernel<<<dim3((N + 255) / 256), dim3(256), 0, stream>>>(cnt, N);

        prep_kernel<<<dim3((E + 255) / 256), dim3(256), 0, stream>>>(
            W0, W1, W2, W3, Wp, receivers, cnt, E);
        scan_kernel<<<dim3(1), dim3(1024), 0, stream>>>(cnt, off, cursor, N);
        fill_kernel<<<dim3((E + 255) / 256), dim3(256), 0, stream>>>(
            receivers, senders, vectors, cursor, edge_of, snd_pos, Y4, E);

        mlp_pos_kernel<<<dim3((E + 63) / 64), dim3(256), 0, stream>>>(
            radial, edge_of, Wp, mix4, E);

        gather_kernel<<<dim3((N + 3) / 4), dim3(256), 0, stream>>>(
            node_feats, snd_pos, Y4, off, mix4, out, N);
    } else {
        // -------- fallback: chunked VALU MLP + atomic scatter --------
        hipMemsetAsync(d_out, 0, (size_t)out_size * sizeof(float), stream);
        size_t per_edge = 256 * sizeof(unsigned short);
        long long chunk_ll = (long long)(ws_size / per_edge);
        int chunk = (chunk_ll > E) ? E : (int)chunk_ll;
        chunk &= ~255;
        if (chunk <= 0) chunk = 256;
        unsigned short* mix = (unsigned short*)d_ws;
        for (int s = 0; s < E; s += chunk) {
            int eend = s + chunk; if (eend > E) eend = E;
            int ne = eend - s;
            mlp_kernel<<<dim3((ne + 255) / 256), dim3(256), 0, stream>>>(
                radial + (size_t)s * 8, W0, W1, W2, W3, mix, ne);
            scatter_kernel<<<dim3((ne + 3) / 4), dim3(256), 0, stream>>>(
                node_feats, vectors, senders, receivers, mix, out, s, eend);
        }
    }
}